// Round 17
// baseline (28.988 us; speedup 1.0000x reference)
//
#include <hip/hip_runtime.h>
#include <stdint.h>

#define B_SZ    8
#define N_PTS   4096
#define C_IN    64
#define C_OUT   64
#define KNN     16
#define ROWS    (B_SZ * N_PTS)      // 32768

typedef __attribute__((ext_vector_type(8))) short v8s;   // 8 bf16 (4 VGPR)
typedef __attribute__((ext_vector_type(4))) float v4f;   // MFMA acc

__device__ inline unsigned short f2bf(float f) {         // RNE f32->bf16
    unsigned int u = __float_as_uint(f);
    return (unsigned short)((u + 0x7FFFu + ((u >> 16) & 1u)) >> 16);
}

__device__ inline v8s pack8(float4 q0, float4 q1) {
    v8s a;
    a[0] = (short)f2bf(q0.x); a[1] = (short)f2bf(q0.y);
    a[2] = (short)f2bf(q0.z); a[3] = (short)f2bf(q0.w);
    a[4] = (short)f2bf(q1.x); a[5] = (short)f2bf(q1.y);
    a[6] = (short)f2bf(q1.z); a[7] = (short)f2bf(q1.w);
    return a;
}

#define PITCH 68

// ---------------------------------------------------------------------------
// Kernel 0: pack combined weights B[k][col] (64x128) into MFMA B-fragment
// order (LDS-staged, coalesced; ~1us).  frag tid = ct*128 + ks*64 + lane:
// cols ct*16+(lane&15), k = ks*32 + 8*(lane>>4) + j.
//   col <  64: B[k][col] = W1[col][k] - W2[col][k]   (cbuf weights)
//   col >= 64: B[k][col] = W2[col-64][k]             (neighbor weights)
// ---------------------------------------------------------------------------
__global__ __launch_bounds__(256) void wprep_kernel(const float* __restrict__ w,
                                                    v8s* __restrict__ wfrag)
{
    __shared__ float wl[2 * C_IN * C_OUT];   // 32 KiB
    const int t = threadIdx.x;
    {
        const float4* src = (const float4*)w;
        float4*       dst = (float4*)wl;
#pragma unroll
        for (int i = 0; i < 8; ++i)
            dst[i * 256 + t] = src[i * 256 + t];
    }
    __syncthreads();

    const int tid  = blockIdx.x * 256 + t;   // 0..1023 (grid = 4)
    const int lane = tid & 63;
    const int ks   = (tid >> 6) & 1;
    const int ct   = tid >> 7;
    const int col  = ct * 16 + (lane & 15);
    const int kb   = ks * 32 + 8 * (lane >> 4);

    v8s f;
#pragma unroll
    for (int j = 0; j < 8; ++j) {
        const int k = kb + j;
        const float v = (col < 64)
            ? (wl[col * 128 + k] - wl[col * 128 + 64 + k])
            : wl[(col - 64) * 128 + 64 + k];
        f[j] = (short)f2bf(v);
    }
    wfrag[tid] = f;
}

// ---------------------------------------------------------------------------
// Kernel 1: FULLY FUSED, zero cross-block deps.  Block = 32 rows of batch b.
//  Phase A: stage 32 x-rows in LDS (coalesced).
//  Phase B: cbuf tile = x·(W1-W2)+bias via MFMA -> LDS only.
//  Phase C: per n, gather the 16 neighbor x-rows (fp32, L2) as an MFMA
//           A-tile, project with W2 frags (D rows = neighbors, cols = o),
//           max over D-rows in-register (3 fmax + 2 shfl_xor), add cbuf,
//           relu, write into LDS.
//  Phase D: transposed coalesced store.
// max_k relu(c + p_k) = relu(c + max_k p_k); max is permutation-invariant.
// ---------------------------------------------------------------------------
__global__ __launch_bounds__(256, 4) void fused_kernel(
    const float* __restrict__ x,
    const v8s*  __restrict__ wfrag,
    const float* __restrict__ bias,
    const int* __restrict__ eidx,
    float* __restrict__ out)
{
    __shared__ float sm[32][PITCH];         // 8.5 KiB: x -> cbuf -> result

    const int t    = threadIdx.x;
    const int lane = t & 63;
    const int wv   = t >> 6;                // wave 0..3
    const int b    = blockIdx.x & 7;        // batch == XCD affinity
    const int tn   = blockIdx.x >> 3;       // 0..127
    const int n0   = tn * 32;
    const int r0g  = b * N_PTS + n0;

    // ---- prefetch eidx for this wave's Phase-C rows (wv*8 .. +7) ----
    const size_t ebase = (size_t)(r0g + wv * 8) * KNN;
    int pa = eidx[ebase + lane]      & (N_PTS - 1);   // rows wv*8 + 0..3
    int pb = eidx[ebase + 64 + lane] & (N_PTS - 1);   // rows wv*8 + 4..7

    // ---- cbuf B-frags (W1-W2), wave = (row half rq) x (col half ch) ----
    const int rq = wv & 1, ch = wv >> 1;
    const int rl0 = rq * 16;
    v8s bC[2][2];
#pragma unroll
    for (int ct = 0; ct < 2; ++ct)
#pragma unroll
        for (int ks = 0; ks < 2; ++ks)
            bC[ct][ks] = wfrag[((ch * 2 + ct) * 2 + ks) * 64 + lane];

    // ---- Phase A: stage 32 x-rows (8 KB) coalesced ----
    {
        const float4* xsrc = (const float4*)(x + (size_t)r0g * C_IN);
#pragma unroll
        for (int i = 0; i < 2; ++i) {
            const int idx = i * 256 + t;
            *(float4*)&sm[idx >> 4][(idx & 15) * 4] = xsrc[idx];
        }
    }
    __syncthreads();

    // ---- Phase B: cbuf tile via MFMA ----
    const int rl   = rl0 + (lane & 15);
    const int koff = 8 * (lane >> 4);
    v8s af[2];
#pragma unroll
    for (int ks = 0; ks < 2; ++ks) {
        const float* xp = &sm[rl][ks * 32 + koff];
        af[ks] = pack8(*(const float4*)xp, *(const float4*)(xp + 4));
    }

    v4f acc[2];
#pragma unroll
    for (int ct = 0; ct < 2; ++ct) {
        const float bv = bias[ch * 32 + ct * 16 + (lane & 15)];
        acc[ct] = (v4f){bv, bv, bv, bv};
    }
#pragma unroll
    for (int ks = 0; ks < 2; ++ks)
#pragma unroll
        for (int ct = 0; ct < 2; ++ct)
            acc[ct] = __builtin_amdgcn_mfma_f32_16x16x32_bf16(
                af[ks], bC[ct][ks], acc[ct], 0, 0, 0);

    // ---- W2 frags for Phase C (loaded late to cap VGPR pressure) ----
    v8s bN[4][2];
#pragma unroll
    for (int ct = 0; ct < 4; ++ct)
#pragma unroll
        for (int ks = 0; ks < 2; ++ks)
            bN[ct][ks] = wfrag[((4 + ct) * 2 + ks) * 64 + lane];

    __syncthreads();                        // all af reads from sm done

    {
        const int orow = rl0 + (lane >> 4) * 4;
        const int ccol = lane & 15;
#pragma unroll
        for (int ct = 0; ct < 2; ++ct)
#pragma unroll
            for (int reg = 0; reg < 4; ++reg)
                sm[orow + reg][ch * 32 + ct * 16 + ccol] = acc[ct][reg];
    }
    __syncthreads();                        // cbuf tile complete

    // ---- Phase C: gather neighbors, project, max, +cbuf, relu ----
    const float* xb = x + (size_t)b * N_PTS * C_IN;
    const int g4 = lane >> 4;               // lane group 0..3

#pragma unroll
    for (int q = 0; q < 8; ++q) {
        // neighbor index for A-row (lane&15) of point n = wv*8+q
        const int src  = (q < 4) ? pa : pb;
        const int idxn = __shfl(src, ((q & 3) << 4) | (lane & 15));

        // A-frags: 16 neighbor rows x K=64 (fp32 gather + RNE pack)
        const float* gp = xb + (size_t)idxn * C_IN + koff;
        const v8s A0 = pack8(*(const float4*)gp,        *(const float4*)(gp + 4));
        const v8s A1 = pack8(*(const float4*)(gp + 32), *(const float4*)(gp + 36));

        // project: D[k][o] for o in 4 col-tiles
        v4f pc[4];
#pragma unroll
        for (int ct = 0; ct < 4; ++ct)
            pc[ct] = (v4f){0.f, 0.f, 0.f, 0.f};
#pragma unroll
        for (int ct = 0; ct < 4; ++ct) {
            pc[ct] = __builtin_amdgcn_mfma_f32_16x16x32_bf16(A0, bN[ct][0], pc[ct], 0, 0, 0);
            pc[ct] = __builtin_amdgcn_mfma_f32_16x16x32_bf16(A1, bN[ct][1], pc[ct], 0, 0, 0);
        }

        // max over 16 D-rows: 4 regs + across 4 lane-groups
        float m[4];
#pragma unroll
        for (int ct = 0; ct < 4; ++ct) {
            float r = fmaxf(fmaxf(pc[ct][0], pc[ct][1]),
                            fmaxf(pc[ct][2], pc[ct][3]));
            r = fmaxf(r, __shfl_xor(r, 16));
            r = fmaxf(r, __shfl_xor(r, 32));
            m[ct] = r;                       // valid in all lanes, col=lane&15
        }
        const float msel = (g4 == 0) ? m[0] : (g4 == 1) ? m[1]
                         : (g4 == 2) ? m[2] : m[3];

        const int nl = wv * 8 + q;
        const int oc = g4 * 16 + (lane & 15);        // == lane: 64 distinct
        const float cv = sm[nl][oc];
        sm[nl][oc] = fmaxf(cv + msel, 0.f);          // relu(max)==max(relu)
    }
    __syncthreads();

    // ---- Phase D: transposed coalesced store ----
    float* ob = out + (size_t)b * C_OUT * N_PTS + n0;
    const int nn = lane & 31;
    const int oh = lane >> 5;
#pragma unroll
    for (int j = 0; j < 8; ++j) {
        const int o = wv * 16 + j * 2 + oh;
        ob[(size_t)o * N_PTS + nn] = sm[nn][o];      // 2x128B segments
    }
}

// ---------------------------------------------------------------------------
extern "C" void kernel_launch(void* const* d_in, const int* in_sizes, int n_in,
                              void* d_out, int out_size, void* d_ws, size_t ws_size,
                              hipStream_t stream)
{
    const float* x    = (const float*)d_in[0];
    const int*   eidx = (const int*)d_in[1];    // int64 in ref -> int32 here
    const float* w    = (const float*)d_in[2];  // (64, 128)
    const float* bias = (const float*)d_in[3];  // (64,)
    float*       out  = (float*)d_out;          // (8, 64, 64, 64) f32

    v8s* wfrag = (v8s*)d_ws;                    // 16 KiB

    wprep_kernel<<<4, 256, 0, stream>>>(w, wfrag);
    fused_kernel<<<ROWS / 32, 256, 0, stream>>>(x, wfrag, bias, eidx, out);
}